// Round 4
// baseline (3358.384 us; speedup 1.0000x reference)
//
#include <hip/hip_runtime.h>

#define NB 16
#define NPTS 4096
#define NS 1024
#define NK 32
#define NCF 64

// All I/O is float32 (values pre-quantized to the bf16 grid by the harness,
// but STORED as f32). Zero workspace bytes used. kNN parks its 32 indices
// (bit-cast to float) in the first 128B of each query's 512B output row;
// mlp_kernel reads them back and fully overwrites the row.

// ---------------- FPS: 1 block per batch, exact reference arithmetic ------
__global__ __launch_bounds__(512) void fps_kernel(
  const float* __restrict__ xyz, float* __restrict__ out)
{
  __shared__ float sxyz[NPTS*3];
  __shared__ float partV[2][8];
  __shared__ int partI[2][8];
  __shared__ int sfps[NS];
  const int b = blockIdx.x, tid = threadIdx.x;

  { // stage xyz -> LDS
    const float4* src=(const float4*)(xyz+(size_t)b*NPTS*3);
    float4* dst=(float4*)sxyz;
    for (int i=tid;i<NPTS*3/4;i+=512) dst[i]=src[i];
  }
  __syncthreads();
  // 8 points per thread in registers (ascending index with tid)
  float px[8],py[8],pz[8],dist[8];
  #pragma unroll
  for (int r=0;r<8;r++){
    int p=tid*8+r;
    px[r]=sxyz[p*3]; py[r]=sxyz[p*3+1]; pz[r]=sxyz[p*3+2];
    dist[r]=1e10f;
  }
  int far=0;
  for (int s=0;s<NS;++s){
    float cx=sxyz[far*3],cy=sxyz[far*3+1],cz=sxyz[far*3+2];
    float bv=-1.0f; int bi=0;
    #pragma unroll
    for (int r=0;r<8;r++){
      float dx=__fsub_rn(px[r],cx);
      float dy=__fsub_rn(py[r],cy);
      float dz=__fsub_rn(pz[r],cz);
      float d2=__fadd_rn(__fadd_rn(__fmul_rn(dx,dx),__fmul_rn(dy,dy)),__fmul_rn(dz,dz));
      float nd=fminf(dist[r],d2);
      dist[r]=nd;
      if (nd>bv){bv=nd;bi=tid*8+r;}   // strict > keeps first index
    }
    // wave allreduce argmax, first-index on ties
    #pragma unroll
    for (int off=1;off<64;off<<=1){
      float ov=__shfl_xor(bv,off);
      int oi=__shfl_xor(bi,off);
      if (ov>bv || (ov==bv && oi<bi)){bv=ov;bi=oi;}
    }
    const int par=s&1;
    if ((tid&63)==0){partV[par][tid>>6]=bv; partI[par][tid>>6]=bi;}
    __syncthreads();
    bv=partV[par][0]; bi=partI[par][0];
    #pragma unroll
    for (int w=1;w<8;w++){
      float ov=partV[par][w]; int oi=partI[par][w];
      if (ov>bv || (ov==bv && oi<bi)){bv=ov;bi=oi;}
    }
    far=bi;
    if (tid==0) sfps[s]=far;
  }
  __syncthreads();
  for (int s=tid;s<NS;s+=512){
    int p=sfps[s];
    size_t o=((size_t)b*NS+s)*3;
    out[o]=sxyz[p*3]; out[o+1]=sxyz[p*3+1]; out[o+2]=sxyz[p*3+2];
  }
}

// ---------------- kNN: 1 wave per block, 1 query per lane -----------------
// keys = (d2_bits<<32)|index  => lexicographic (d2, idx): exact stable top_k.
__global__ __launch_bounds__(64) void knn_kernel(
  const float* __restrict__ xyz, const float* __restrict__ newxyz,
  float* __restrict__ out2)
{
  __shared__ float sx[NPTS*3];
  const int tid=threadIdx.x;
  const int b=blockIdx.x>>4;
  {
    const float4* src=(const float4*)(xyz+(size_t)b*NPTS*3);
    float4* dst=(float4*)sx;
    for (int i=tid;i<NPTS*3/4;i+=64) dst[i]=src[i];
  }
  __syncthreads();
  const int q=blockIdx.x*64+tid;
  float ax=newxyz[(size_t)q*3],ay=newxyz[(size_t)q*3+1],az=newxyz[(size_t)q*3+2];
  float a2=__fadd_rn(__fadd_rn(__fmul_rn(ax,ax),__fmul_rn(ay,ay)),__fmul_rn(az,az));
  unsigned long long kA[NK];
  #pragma unroll
  for (int p=0;p<NK;p++) kA[p]=~0ull;
  for (int n=0;n<NPTS;++n){
    float bx=sx[n*3],by=sx[n*3+1],bz=sx[n*3+2];
    float b2=__fadd_rn(__fadd_rn(__fmul_rn(bx,bx),__fmul_rn(by,by)),__fmul_rn(bz,bz));
    float ab=__fadd_rn(__fadd_rn(__fmul_rn(ax,bx),__fmul_rn(ay,by)),__fmul_rn(az,bz));
    float t=__fadd_rn(__fsub_rn(a2,__fmul_rn(2.0f,ab)),b2);
    float d2=fmaxf(t,0.0f);
    unsigned long long key=(((unsigned long long)__float_as_uint(d2))<<32)|(unsigned)n;
    if (key<kA[NK-1]){
      #pragma unroll
      for (int p=NK-1;p>0;--p){
        bool cm1=key<kA[p-1];
        bool cp=key<kA[p];
        kA[p]=cm1?kA[p-1]:(cp?key:kA[p]);
      }
      if (key<kA[0]) kA[0]=key;
    }
  }
  // park indices (bit-cast) in the first 128B of this query's output row
  float4* kp=(float4*)(out2+(size_t)q*128);
  #pragma unroll
  for (int p=0;p<NK;p+=4){
    float4 u;
    u.x=__int_as_float((int)(unsigned)kA[p]);
    u.y=__int_as_float((int)(unsigned)kA[p+1]);
    u.z=__int_as_float((int)(unsigned)kA[p+2]);
    u.w=__int_as_float((int)(unsigned)kA[p+3]);
    kp[p/4]=u;
  }
}

// ---------------- fused group + MLP(3) + maxpool --------------------------
// 128 threads = 4 queries x 32 neighbor rows. Activations in LDS stride 67
// (2-way bank aliasing = free). Weights read from global: wave-uniform
// addresses -> scalar loads / L1 broadcast.
__global__ __launch_bounds__(128) void mlp_kernel(
  const float* __restrict__ feat, const float* __restrict__ xyz,
  const float* __restrict__ newxyz,
  const float* __restrict__ W0,const float* __restrict__ b0,
  const float* __restrict__ g0,const float* __restrict__ be0,
  const float* __restrict__ m0,const float* __restrict__ v0,
  const float* __restrict__ W1,const float* __restrict__ b1,
  const float* __restrict__ g1,const float* __restrict__ be1,
  const float* __restrict__ m1,const float* __restrict__ v1,
  const float* __restrict__ W2,const float* __restrict__ b2,
  const float* __restrict__ g2,const float* __restrict__ be2,
  const float* __restrict__ m2,const float* __restrict__ v2,
  float* __restrict__ out2)
{
  __shared__ float sX[128*67];
  const int tid=threadIdx.x;
  const int q=blockIdx.x*4+(tid>>5);
  const int k=tid&31;
  const int b=q>>10;
  const int pt=__float_as_int(out2[(size_t)q*128+k]);

  float* myx=sX+tid*67;
  {
    const float* nx=newxyz+(size_t)q*3;
    const float* pp=xyz+((size_t)b*NPTS+pt)*3;
    myx[0]=pp[0]-nx[0]; myx[1]=pp[1]-nx[1]; myx[2]=pp[2]-nx[2];
    const float4* fp=(const float4*)(feat+((size_t)b*NPTS+pt)*NCF);
    #pragma unroll
    for (int i=0;i<16;i++){
      float4 u=fp[i]; float* d=myx+3+i*4;
      d[0]=u.x; d[1]=u.y; d[2]=u.z; d[3]=u.w;
    }
  }
  // layer 1: 67 -> 64
  float acc[64];
  #pragma unroll
  for (int c=0;c<64;c++) acc[c]=b0[c];
  #pragma unroll 2
  for (int j=0;j<67;++j){
    float xj=myx[j];
    const float* wr=W0+j*64;
    #pragma unroll
    for (int c=0;c<64;c++) acc[c]=fmaf(xj,wr[c],acc[c]);
  }
  #pragma unroll
  for (int c=0;c<64;c++){
    float A=g0[c]*rsqrtf(v0[c]+1e-3f);
    myx[c]=fmaf(A,fmaxf(acc[c],0.0f),be0[c]-m0[c]*A);
  }
  // layer 2: 64 -> 64
  #pragma unroll
  for (int c=0;c<64;c++) acc[c]=b1[c];
  #pragma unroll 2
  for (int j=0;j<64;++j){
    float xj=myx[j];
    const float* wr=W1+j*64;
    #pragma unroll
    for (int c=0;c<64;c++) acc[c]=fmaf(xj,wr[c],acc[c]);
  }
  #pragma unroll
  for (int c=0;c<64;c++){
    float A=g1[c]*rsqrtf(v1[c]+1e-3f);
    myx[c]=fmaf(A,fmaxf(acc[c],0.0f),be1[c]-m1[c]*A);
  }
  // layer 3: 64 -> 128
  float y[128];
  #pragma unroll
  for (int c=0;c<128;c++) y[c]=b2[c];
  #pragma unroll 1
  for (int j=0;j<64;++j){
    float xj=myx[j];
    const float* wr=W2+j*128;
    #pragma unroll
    for (int c=0;c<128;c++) y[c]=fmaf(xj,wr[c],y[c]);
  }
  #pragma unroll
  for (int c=0;c<128;c++){
    float A=g2[c]*rsqrtf(v2[c]+1e-3f);
    y[c]=fmaf(A,fmaxf(y[c],0.0f),be2[c]-m2[c]*A);
  }
  // max over the 32 rows of this query (butterfly within 32-lane group)
  #pragma unroll
  for (int c=0;c<128;c++){
    float v=y[c];
    v=fmaxf(v,__shfl_xor(v,1));
    v=fmaxf(v,__shfl_xor(v,2));
    v=fmaxf(v,__shfl_xor(v,4));
    v=fmaxf(v,__shfl_xor(v,8));
    v=fmaxf(v,__shfl_xor(v,16));
    y[c]=v;
  }
  if (k==0){
    float4* op=(float4*)(out2+(size_t)q*128);
    #pragma unroll
    for (int c=0;c<128;c+=4)
      op[c/4]=make_float4(y[c],y[c+1],y[c+2],y[c+3]);
  }
}

extern "C" void kernel_launch(void* const* d_in, const int* in_sizes, int n_in,
                              void* d_out, int out_size, void* d_ws, size_t ws_size,
                              hipStream_t stream)
{
  const float* xyz=(const float*)d_in[0];
  const float* feat=(const float*)d_in[1];
  float* out=(float*)d_out;
  float* out2=out+(size_t)NB*NS*3;     // pooled-feature region
  (void)d_ws; (void)ws_size;

  fps_kernel<<<NB,512,0,stream>>>(xyz,out);
  knn_kernel<<<NB*16,64,0,stream>>>(xyz,out,out2);
  mlp_kernel<<<NB*NS/4,128,0,stream>>>(feat,xyz,out,
    (const float*)d_in[2],(const float*)d_in[3],
    (const float*)d_in[4],(const float*)d_in[5],
    (const float*)d_in[6],(const float*)d_in[7],
    (const float*)d_in[8],(const float*)d_in[9],
    (const float*)d_in[10],(const float*)d_in[11],
    (const float*)d_in[12],(const float*)d_in[13],
    (const float*)d_in[14],(const float*)d_in[15],
    (const float*)d_in[16],(const float*)d_in[17],
    (const float*)d_in[18],(const float*)d_in[19],
    out2);
}

// Round 5
// 2649.486 us; speedup vs baseline: 1.2676x; 1.2676x over previous
//
#include <hip/hip_runtime.h>

#define NB 16
#define NPTS 4096
#define NS 1024
#define NK 32
#define NCF 64

// All I/O is float32. Zero workspace bytes used. kNN parks its 32 indices
// (bit-cast to float) in the first 128B of each query's 512B output row;
// mlp_kernel reads them back and fully overwrites the row.

#define DPP_SHR1   0x111
#define DPP_SHR2   0x112
#define DPP_SHR4   0x114
#define DPP_SHR8   0x118
#define DPP_BCAST15 0x142
#define DPP_BCAST31 0x143

// one max step of a wave64 u64-key reduction via DPP (invalid lanes keep self)
#define DPP_MAX_STEP(cur, CTRL) do{ \
  int lo_=__builtin_amdgcn_update_dpp((int)(unsigned)(cur),(int)(unsigned)(cur),CTRL,0xF,0xF,false); \
  int hi_=__builtin_amdgcn_update_dpp((int)(unsigned)((cur)>>32),(int)(unsigned)((cur)>>32),CTRL,0xF,0xF,false); \
  unsigned long long nk_=(((unsigned long long)(unsigned)hi_)<<32)|(unsigned)lo_; \
  if (nk_>(cur)) (cur)=nk_; \
}while(0)

// ---------------- FPS: 1 block/batch, 256 thr, DPP argmax ----------------
// key = (dist_bits<<32) | (4095-idx): u64 max == max dist, first index.
__global__ __launch_bounds__(256) void fps_kernel(
  const float* __restrict__ xyz, float* __restrict__ out)
{
  __shared__ float sxyz[NPTS*3];
  __shared__ unsigned long long skey[2][4];
  __shared__ int sfps[NS];
  const int b = blockIdx.x, tid = threadIdx.x;

  { // stage xyz -> LDS
    const float4* src=(const float4*)(xyz+(size_t)b*NPTS*3);
    float4* dst=(float4*)sxyz;
    for (int i=tid;i<NPTS*3/4;i+=256) dst[i]=src[i];
  }
  __syncthreads();
  // 16 points per thread in registers (ascending index with tid)
  float px[16],py[16],pz[16],dist[16];
  #pragma unroll
  for (int r=0;r<16;r++){
    int p=tid*16+r;
    px[r]=sxyz[p*3]; py[r]=sxyz[p*3+1]; pz[r]=sxyz[p*3+2];
    dist[r]=1e10f;
  }
  int far=0;
  for (int s=0;s<NS;++s){
    float cx=sxyz[far*3],cy=sxyz[far*3+1],cz=sxyz[far*3+2];
    float bv=-1.0f; int bslot=0;
    #pragma unroll
    for (int r=0;r<16;r++){
      float dx=__fsub_rn(px[r],cx);
      float dy=__fsub_rn(py[r],cy);
      float dz=__fsub_rn(pz[r],cz);
      float d2=__fadd_rn(__fadd_rn(__fmul_rn(dx,dx),__fmul_rn(dy,dy)),__fmul_rn(dz,dz));
      float nd=fminf(dist[r],d2);
      dist[r]=nd;
      if (nd>bv){bv=nd;bslot=r;}      // strict > keeps first index in lane
    }
    int bidx=tid*16+bslot;
    unsigned long long cur=(((unsigned long long)__float_as_uint(bv))<<32)
                           |(unsigned)(4095-bidx);
    // wave64 max via DPP: after 6 steps lane63 holds the wave max
    DPP_MAX_STEP(cur,DPP_SHR1);
    DPP_MAX_STEP(cur,DPP_SHR2);
    DPP_MAX_STEP(cur,DPP_SHR4);
    DPP_MAX_STEP(cur,DPP_SHR8);
    DPP_MAX_STEP(cur,DPP_BCAST15);
    DPP_MAX_STEP(cur,DPP_BCAST31);
    const int par=s&1;
    if ((tid&63)==63) skey[par][tid>>6]=cur;
    __syncthreads();
    unsigned long long m=skey[par][0];
    #pragma unroll
    for (int w=1;w<4;w++){ unsigned long long o=skey[par][w]; if (o>m) m=o; }
    far=4095-(int)(m&0xFFFFFFFFu);
    if (tid==0) sfps[s]=far;
  }
  __syncthreads();
  for (int s=tid;s<NS;s+=256){
    int p=sfps[s];
    size_t o=((size_t)b*NS+s)*3;
    out[o]=sxyz[p*3]; out[o+1]=sxyz[p*3+1]; out[o+2]=sxyz[p*3+2];
  }
}

// ---------------- kNN: 1 wave/block, 16 queries, 4 lanes/query ------------
// Each lane scans a strided quarter (1024 pts) keeping sorted top-32 of
// keys (d2_bits<<32)|idx; then exact 4-way merge (keys unique) gives the
// stable global top-32 per query. Merge buffer aliases sx (barrier-sep).
__global__ __launch_bounds__(64) void knn_kernel(
  const float* __restrict__ xyz, const float* __restrict__ newxyz,
  float* __restrict__ out2)
{
  __shared__ __align__(16) float sx[NPTS*3];   // 48 KB
  const int tid=threadIdx.x;
  const int gq=blockIdx.x*16+(tid>>2);  // global query for scan phase
  const int part=tid&3;
  const int b=gq>>10;
  {
    const float4* src=(const float4*)(xyz+(size_t)b*NPTS*3);
    float4* dst=(float4*)sx;
    for (int i=tid;i<NPTS*3/4;i+=64) dst[i]=src[i];
  }
  __syncthreads();
  float ax=newxyz[(size_t)gq*3],ay=newxyz[(size_t)gq*3+1],az=newxyz[(size_t)gq*3+2];
  float a2=__fadd_rn(__fadd_rn(__fmul_rn(ax,ax),__fmul_rn(ay,ay)),__fmul_rn(az,az));
  unsigned long long kA[NK];
  #pragma unroll
  for (int p=0;p<NK;p++) kA[p]=~0ull;
  #pragma unroll 2
  for (int t=0;t<NPTS/4;++t){
    int n=(t<<2)|part;
    float bx=sx[n*3],by=sx[n*3+1],bz=sx[n*3+2];
    float b2=__fadd_rn(__fadd_rn(__fmul_rn(bx,bx),__fmul_rn(by,by)),__fmul_rn(bz,bz));
    float ab=__fadd_rn(__fadd_rn(__fmul_rn(ax,bx),__fmul_rn(ay,by)),__fmul_rn(az,bz));
    float tt=__fadd_rn(__fsub_rn(a2,__fmul_rn(2.0f,ab)),b2);
    float d2=fmaxf(tt,0.0f);
    unsigned long long key=(((unsigned long long)__float_as_uint(d2))<<32)|(unsigned)n;
    if (key<kA[NK-1]){
      #pragma unroll
      for (int p=NK-1;p>0;--p){
        bool cm1=key<kA[p-1];
        bool cp=key<kA[p];
        kA[p]=cm1?kA[p-1]:(cp?key:kA[p]);
      }
      if (key<kA[0]) kA[0]=key;
    }
  }
  __syncthreads();              // all lanes done reading sx
  // dump per-lane sorted lists into (aliased) LDS, padded to kill conflicts
  unsigned long long* skeys=(unsigned long long*)sx;  // [64][33]
  {
    unsigned long long* row=skeys+(size_t)tid*33;
    #pragma unroll
    for (int p=0;p<NK;p++) row[p]=kA[p];
  }
  __syncthreads();
  // lanes 0..15: 4-way merge of rows 4l..4l+3 -> 32 smallest, in order
  if (tid<16){
    const unsigned long long* r0=skeys+(size_t)(4*tid+0)*33;
    const unsigned long long* r1=skeys+(size_t)(4*tid+1)*33;
    const unsigned long long* r2=skeys+(size_t)(4*tid+2)*33;
    const unsigned long long* r3=skeys+(size_t)(4*tid+3)*33;
    int h0=0,h1=0,h2=0,h3=0;
    unsigned long long c0=r0[0],c1=r1[0],c2=r2[0],c3=r3[0];
    float* orow=out2+(size_t)(blockIdx.x*16+tid)*128;
    for (int i=0;i<NK;++i){
      bool s01=c1<c0; unsigned long long m01=s01?c1:c0;
      bool s23=c3<c2; unsigned long long m23=s23?c3:c2;
      bool sm=m23<m01; unsigned long long m=sm?m23:m01;
      orow[i]=__int_as_float((int)(unsigned)(m&0xFFFFFFFFu));
      int w=sm?(s23?3:2):(s01?1:0);
      if (w==0){ h0++; c0=(h0<NK)?r0[h0]:~0ull; }
      else if (w==1){ h1++; c1=(h1<NK)?r1[h1]:~0ull; }
      else if (w==2){ h2++; c2=(h2<NK)?r2[h2]:~0ull; }
      else { h3++; c3=(h3<NK)?r3[h3]:~0ull; }
    }
  }
}

// ---------------- fused group + MLP(3) + maxpool --------------------------
__global__ __launch_bounds__(128) void mlp_kernel(
  const float* __restrict__ feat, const float* __restrict__ xyz,
  const float* __restrict__ newxyz,
  const float* __restrict__ W0,const float* __restrict__ b0,
  const float* __restrict__ g0,const float* __restrict__ be0,
  const float* __restrict__ m0,const float* __restrict__ v0,
  const float* __restrict__ W1,const float* __restrict__ b1,
  const float* __restrict__ g1,const float* __restrict__ be1,
  const float* __restrict__ m1,const float* __restrict__ v1,
  const float* __restrict__ W2,const float* __restrict__ b2,
  const float* __restrict__ g2,const float* __restrict__ be2,
  const float* __restrict__ m2,const float* __restrict__ v2,
  float* __restrict__ out2)
{
  __shared__ float sX[128*67];
  const int tid=threadIdx.x;
  const int q=blockIdx.x*4+(tid>>5);
  const int k=tid&31;
  const int b=q>>10;
  const int pt=__float_as_int(out2[(size_t)q*128+k]);

  float* myx=sX+tid*67;
  {
    const float* nx=newxyz+(size_t)q*3;
    const float* pp=xyz+((size_t)b*NPTS+pt)*3;
    myx[0]=pp[0]-nx[0]; myx[1]=pp[1]-nx[1]; myx[2]=pp[2]-nx[2];
    const float4* fp=(const float4*)(feat+((size_t)b*NPTS+pt)*NCF);
    #pragma unroll
    for (int i=0;i<16;i++){
      float4 u=fp[i]; float* d=myx+3+i*4;
      d[0]=u.x; d[1]=u.y; d[2]=u.z; d[3]=u.w;
    }
  }
  // layer 1: 67 -> 64
  float acc[64];
  #pragma unroll
  for (int c=0;c<64;c++) acc[c]=b0[c];
  #pragma unroll 2
  for (int j=0;j<67;++j){
    float xj=myx[j];
    const float* wr=W0+j*64;
    #pragma unroll
    for (int c=0;c<64;c++) acc[c]=fmaf(xj,wr[c],acc[c]);
  }
  #pragma unroll
  for (int c=0;c<64;c++){
    float A=g0[c]*rsqrtf(v0[c]+1e-3f);
    myx[c]=fmaf(A,fmaxf(acc[c],0.0f),be0[c]-m0[c]*A);
  }
  // layer 2: 64 -> 64
  #pragma unroll
  for (int c=0;c<64;c++) acc[c]=b1[c];
  #pragma unroll 2
  for (int j=0;j<64;++j){
    float xj=myx[j];
    const float* wr=W1+j*64;
    #pragma unroll
    for (int c=0;c<64;c++) acc[c]=fmaf(xj,wr[c],acc[c]);
  }
  #pragma unroll
  for (int c=0;c<64;c++){
    float A=g1[c]*rsqrtf(v1[c]+1e-3f);
    myx[c]=fmaf(A,fmaxf(acc[c],0.0f),be1[c]-m1[c]*A);
  }
  // layer 3: 64 -> 128
  float y[128];
  #pragma unroll
  for (int c=0;c<128;c++) y[c]=b2[c];
  #pragma unroll 1
  for (int j=0;j<64;++j){
    float xj=myx[j];
    const float* wr=W2+j*128;
    #pragma unroll
    for (int c=0;c<128;c++) y[c]=fmaf(xj,wr[c],y[c]);
  }
  #pragma unroll
  for (int c=0;c<128;c++){
    float A=g2[c]*rsqrtf(v2[c]+1e-3f);
    y[c]=fmaf(A,fmaxf(y[c],0.0f),be2[c]-m2[c]*A);
  }
  // max over the 32 rows of this query (butterfly within 32-lane group)
  #pragma unroll
  for (int c=0;c<128;c++){
    float v=y[c];
    v=fmaxf(v,__shfl_xor(v,1));
    v=fmaxf(v,__shfl_xor(v,2));
    v=fmaxf(v,__shfl_xor(v,4));
    v=fmaxf(v,__shfl_xor(v,8));
    v=fmaxf(v,__shfl_xor(v,16));
    y[c]=v;
  }
  if (k==0){
    float4* op=(float4*)(out2+(size_t)q*128);
    #pragma unroll
    for (int c=0;c<128;c+=4)
      op[c/4]=make_float4(y[c],y[c+1],y[c+2],y[c+3]);
  }
}

extern "C" void kernel_launch(void* const* d_in, const int* in_sizes, int n_in,
                              void* d_out, int out_size, void* d_ws, size_t ws_size,
                              hipStream_t stream)
{
  const float* xyz=(const float*)d_in[0];
  const float* feat=(const float*)d_in[1];
  float* out=(float*)d_out;
  float* out2=out+(size_t)NB*NS*3;     // pooled-feature region
  (void)d_ws; (void)ws_size;

  fps_kernel<<<NB,256,0,stream>>>(xyz,out);
  knn_kernel<<<NB*NS/16,64,0,stream>>>(xyz,out,out2);
  mlp_kernel<<<NB*NS/4,128,0,stream>>>(feat,xyz,out,
    (const float*)d_in[2],(const float*)d_in[3],
    (const float*)d_in[4],(const float*)d_in[5],
    (const float*)d_in[6],(const float*)d_in[7],
    (const float*)d_in[8],(const float*)d_in[9],
    (const float*)d_in[10],(const float*)d_in[11],
    (const float*)d_in[12],(const float*)d_in[13],
    (const float*)d_in[14],(const float*)d_in[15],
    (const float*)d_in[16],(const float*)d_in[17],
    (const float*)d_in[18],(const float*)d_in[19],
    out2);
}

// Round 6
// 2326.826 us; speedup vs baseline: 1.4433x; 1.1387x over previous
//
#include <hip/hip_runtime.h>

#define NB 16
#define NPTS 4096
#define NS 1024
#define NK 32
#define NCF 64

// All I/O is float32. Zero workspace bytes used. kNN parks its 32 indices
// (bit-cast to float) in the first 128B of each query's 512B output row;
// mlp_kernel reads them back and fully overwrites the row. Row ORDER of the
// 32 neighbors is irrelevant (max-pool) — only the index SET must be exact.

#define F_INF __int_as_float(0x7f800000)

#define DPP_SHR1   0x111
#define DPP_SHR2   0x112
#define DPP_SHR4   0x114
#define DPP_SHR8   0x118
#define DPP_BCAST15 0x142
#define DPP_BCAST31 0x143

// one max step of a wave64 u64-key reduction via DPP (invalid lanes keep self)
#define DPP_MAX_STEP(cur, CTRL) do{ \
  int lo_=__builtin_amdgcn_update_dpp((int)(unsigned)(cur),(int)(unsigned)(cur),CTRL,0xF,0xF,false); \
  int hi_=__builtin_amdgcn_update_dpp((int)(unsigned)((cur)>>32),(int)(unsigned)((cur)>>32),CTRL,0xF,0xF,false); \
  unsigned long long nk_=(((unsigned long long)(unsigned)hi_)<<32)|(unsigned)lo_; \
  if (nk_>(cur)) (cur)=nk_; \
}while(0)

// ---------------- FPS: 1 block/batch, 512 thr, DPP argmax ----------------
// key = (dist_bits<<32) | (4095-idx): u64 max == max dist, first index.
__global__ __launch_bounds__(512) void fps_kernel(
  const float* __restrict__ xyz, float* __restrict__ out)
{
  __shared__ float sxyz[NPTS*3];
  __shared__ unsigned long long skey[2][8];
  __shared__ int sfps[NS];
  const int b = blockIdx.x, tid = threadIdx.x;

  { // stage xyz -> LDS
    const float4* src=(const float4*)(xyz+(size_t)b*NPTS*3);
    float4* dst=(float4*)sxyz;
    for (int i=tid;i<NPTS*3/4;i+=512) dst[i]=src[i];
  }
  __syncthreads();
  // 8 points per thread in registers (ascending index with tid)
  float px[8],py[8],pz[8],dist[8];
  #pragma unroll
  for (int r=0;r<8;r++){
    int p=tid*8+r;
    px[r]=sxyz[p*3]; py[r]=sxyz[p*3+1]; pz[r]=sxyz[p*3+2];
    dist[r]=1e10f;
  }
  int far=0;
  for (int s=0;s<NS;++s){
    float cx=sxyz[far*3],cy=sxyz[far*3+1],cz=sxyz[far*3+2];
    float bv=-1.0f; int bslot=0;
    #pragma unroll
    for (int r=0;r<8;r++){
      float dx=__fsub_rn(px[r],cx);
      float dy=__fsub_rn(py[r],cy);
      float dz=__fsub_rn(pz[r],cz);
      float d2=__fadd_rn(__fadd_rn(__fmul_rn(dx,dx),__fmul_rn(dy,dy)),__fmul_rn(dz,dz));
      float nd=fminf(dist[r],d2);
      dist[r]=nd;
      if (nd>bv){bv=nd;bslot=r;}      // strict > keeps first index in lane
    }
    int bidx=tid*8+bslot;
    unsigned long long cur=(((unsigned long long)__float_as_uint(bv))<<32)
                           |(unsigned)(4095-bidx);
    DPP_MAX_STEP(cur,DPP_SHR1);
    DPP_MAX_STEP(cur,DPP_SHR2);
    DPP_MAX_STEP(cur,DPP_SHR4);
    DPP_MAX_STEP(cur,DPP_SHR8);
    DPP_MAX_STEP(cur,DPP_BCAST15);
    DPP_MAX_STEP(cur,DPP_BCAST31);
    const int par=s&1;
    if ((tid&63)==63) skey[par][tid>>6]=cur;
    __syncthreads();
    unsigned long long m=skey[par][0];
    #pragma unroll
    for (int w=1;w<8;w++){ unsigned long long o=skey[par][w]; if (o>m) m=o; }
    far=4095-(int)(m&0xFFFFFFFFu);
    if (tid==0) sfps[s]=far;
  }
  __syncthreads();
  for (int s=tid;s<NS;s+=512){
    int p=sfps[s];
    size_t o=((size_t)b*NS+s)*3;
    out[o]=sxyz[p*3]; out[o+1]=sxyz[p*3+1]; out[o+2]=sxyz[p*3+2];
  }
}

// ---------------- kNN: 256 thr (4 waves), 64 queries/block ----------------
// 4 lanes/query scan strided quarters keeping sorted (d2,idx) top-32 per
// lane (f32 dist + int idx split lists); exact 4-way merge per query via
// LDS dump (2 phases aliasing the coord buffer). Output = index SET only.
__global__ __launch_bounds__(256) void knn_kernel(
  const float* __restrict__ xyz, const float* __restrict__ newxyz,
  float* __restrict__ out2)
{
  __shared__ __align__(16) float sbuf[NPTS*3];   // 48 KB, aliased for merge
  const int tid=threadIdx.x;
  const int qloc=tid>>2;                 // 0..63
  const int part=tid&3;
  const int gq=blockIdx.x*64+qloc;
  const int b=gq>>10;
  {
    const float4* src=(const float4*)(xyz+(size_t)b*NPTS*3);
    float4* dst=(float4*)sbuf;
    for (int i=tid;i<NPTS*3/4;i+=256) dst[i]=src[i];
  }
  __syncthreads();
  float ax=newxyz[(size_t)gq*3],ay=newxyz[(size_t)gq*3+1],az=newxyz[(size_t)gq*3+2];
  float a2=__fadd_rn(__fadd_rn(__fmul_rn(ax,ax),__fmul_rn(ay,ay)),__fmul_rn(az,az));
  float kD[NK]; int kI[NK];
  #pragma unroll
  for (int p=0;p<NK;p++){kD[p]=F_INF;kI[p]=0x7FFFFFFF;}
  #pragma unroll 2
  for (int t=0;t<NPTS/4;++t){
    int n=(t<<2)|part;
    float bx=sbuf[n*3],by=sbuf[n*3+1],bz=sbuf[n*3+2];
    float b2=__fadd_rn(__fadd_rn(__fmul_rn(bx,bx),__fmul_rn(by,by)),__fmul_rn(bz,bz));
    float ab=__fadd_rn(__fadd_rn(__fmul_rn(ax,bx),__fmul_rn(ay,by)),__fmul_rn(az,bz));
    float tt=__fadd_rn(__fsub_rn(a2,__fmul_rn(2.0f,ab)),b2);
    float d2=fmaxf(tt,0.0f);
    if (d2<kD[NK-1]){                    // strict <: in-lane stability
      #pragma unroll
      for (int p=NK-1;p>0;--p){
        bool cm1=d2<kD[p-1];
        bool cp=d2<kD[p];
        kD[p]=cm1?kD[p-1]:(cp?d2:kD[p]);
        kI[p]=cm1?kI[p-1]:(cp?n:kI[p]);
      }
      if (d2<kD[0]){kD[0]=d2;kI[0]=n;}
    }
  }
  __syncthreads();                        // done reading coords
  float* sD=sbuf;                         // [128][33] f32
  int*   sI=(int*)(sbuf+128*33);          // [128][33] int
  #pragma unroll 1
  for (int phase=0;phase<2;++phase){
    if ((tid>>7)==phase){
      int row=tid&127;
      #pragma unroll
      for (int p=0;p<NK;p++){ sD[row*33+p]=kD[p]; sI[row*33+p]=kI[p]; }
    }
    __syncthreads();
    if (tid<32){
      const int r0=4*tid, r1=r0+1, r2=r0+2, r3=r0+3;
      int h0=0,h1=0,h2=0,h3=0;
      float c0d=sD[r0*33],c1d=sD[r1*33],c2d=sD[r2*33],c3d=sD[r3*33];
      int   c0i=sI[r0*33],c1i=sI[r1*33],c2i=sI[r2*33],c3i=sI[r3*33];
      float* orow=out2+(size_t)(blockIdx.x*64+phase*32+tid)*128;
      for (int i=0;i<NK;++i){
        bool s01=(c1d<c0d)||(c1d==c0d&&c1i<c0i);
        float m01d=s01?c1d:c0d; int m01i=s01?c1i:c0i;
        bool s23=(c3d<c2d)||(c3d==c2d&&c3i<c2i);
        float m23d=s23?c3d:c2d; int m23i=s23?c3i:c2i;
        bool sm=(m23d<m01d)||(m23d==m01d&&m23i<m01i);
        orow[i]=__int_as_float(sm?m23i:m01i);
        int w=sm?(s23?3:2):(s01?1:0);
        if (w==0){h0++; bool v=h0<NK; c0d=v?sD[r0*33+h0]:F_INF; c0i=v?sI[r0*33+h0]:0x7FFFFFFF;}
        else if (w==1){h1++; bool v=h1<NK; c1d=v?sD[r1*33+h1]:F_INF; c1i=v?sI[r1*33+h1]:0x7FFFFFFF;}
        else if (w==2){h2++; bool v=h2<NK; c2d=v?sD[r2*33+h2]:F_INF; c2i=v?sI[r2*33+h2]:0x7FFFFFFF;}
        else {h3++; bool v=h3<NK; c3d=v?sD[r3*33+h3]:F_INF; c3i=v?sI[r3*33+h3]:0x7FFFFFFF;}
      }
    }
    __syncthreads();
  }
}

// ---------------- fused group + MLP(3) + maxpool --------------------------
// 128 threads = 4 queries x 32 neighbor rows. Layer 3 in two 64-col chunks
// to keep VGPRs < 128 (no scratch spill).
__global__ __launch_bounds__(128) void mlp_kernel(
  const float* __restrict__ feat, const float* __restrict__ xyz,
  const float* __restrict__ newxyz,
  const float* __restrict__ W0,const float* __restrict__ b0,
  const float* __restrict__ g0,const float* __restrict__ be0,
  const float* __restrict__ m0,const float* __restrict__ v0,
  const float* __restrict__ W1,const float* __restrict__ b1,
  const float* __restrict__ g1,const float* __restrict__ be1,
  const float* __restrict__ m1,const float* __restrict__ v1,
  const float* __restrict__ W2,const float* __restrict__ b2,
  const float* __restrict__ g2,const float* __restrict__ be2,
  const float* __restrict__ m2,const float* __restrict__ v2,
  float* __restrict__ out2)
{
  __shared__ float sX[128*67];
  const int tid=threadIdx.x;
  const int q=blockIdx.x*4+(tid>>5);
  const int k=tid&31;
  const int b=q>>10;
  const int pt=__float_as_int(out2[(size_t)q*128+k]);

  float* myx=sX+tid*67;
  {
    const float* nx=newxyz+(size_t)q*3;
    const float* pp=xyz+((size_t)b*NPTS+pt)*3;
    myx[0]=pp[0]-nx[0]; myx[1]=pp[1]-nx[1]; myx[2]=pp[2]-nx[2];
    const float4* fp=(const float4*)(feat+((size_t)b*NPTS+pt)*NCF);
    #pragma unroll
    for (int i=0;i<16;i++){
      float4 u=fp[i]; float* d=myx+3+i*4;
      d[0]=u.x; d[1]=u.y; d[2]=u.z; d[3]=u.w;
    }
  }
  float acc[64];
  // layer 1: 67 -> 64
  #pragma unroll
  for (int c=0;c<64;c++) acc[c]=b0[c];
  #pragma unroll 2
  for (int j=0;j<67;++j){
    float xj=myx[j];
    const float* wr=W0+j*64;
    #pragma unroll
    for (int c=0;c<64;c++) acc[c]=fmaf(xj,wr[c],acc[c]);
  }
  #pragma unroll
  for (int c=0;c<64;c++){
    float A=g0[c]*rsqrtf(v0[c]+1e-3f);
    myx[c]=fmaf(A,fmaxf(acc[c],0.0f),be0[c]-m0[c]*A);
  }
  // layer 2: 64 -> 64
  #pragma unroll
  for (int c=0;c<64;c++) acc[c]=b1[c];
  #pragma unroll 2
  for (int j=0;j<64;++j){
    float xj=myx[j];
    const float* wr=W1+j*64;
    #pragma unroll
    for (int c=0;c<64;c++) acc[c]=fmaf(xj,wr[c],acc[c]);
  }
  #pragma unroll
  for (int c=0;c<64;c++){
    float A=g1[c]*rsqrtf(v1[c]+1e-3f);
    myx[c]=fmaf(A,fmaxf(acc[c],0.0f),be1[c]-m1[c]*A);
  }
  // layer 3: 64 -> 128, two 64-col chunks (keeps VGPR low)
  #pragma unroll 1
  for (int ch=0;ch<2;++ch){
    const int co=ch*64;
    #pragma unroll
    for (int c=0;c<64;c++) acc[c]=b2[co+c];
    #pragma unroll 2
    for (int j=0;j<64;++j){
      float xj=myx[j];
      const float* wr=W2+j*128+co;
      #pragma unroll
      for (int c=0;c<64;c++) acc[c]=fmaf(xj,wr[c],acc[c]);
    }
    #pragma unroll
    for (int c=0;c<64;c++){
      float A=g2[co+c]*rsqrtf(v2[co+c]+1e-3f);
      float v=fmaf(A,fmaxf(acc[c],0.0f),be2[co+c]-m2[co+c]*A);
      v=fmaxf(v,__shfl_xor(v,1));
      v=fmaxf(v,__shfl_xor(v,2));
      v=fmaxf(v,__shfl_xor(v,4));
      v=fmaxf(v,__shfl_xor(v,8));
      v=fmaxf(v,__shfl_xor(v,16));
      acc[c]=v;
    }
    if (k==0){
      float4* op=(float4*)(out2+(size_t)q*128+co);
      #pragma unroll
      for (int c=0;c<64;c+=4)
        op[c/4]=make_float4(acc[c],acc[c+1],acc[c+2],acc[c+3]);
    }
  }
}

extern "C" void kernel_launch(void* const* d_in, const int* in_sizes, int n_in,
                              void* d_out, int out_size, void* d_ws, size_t ws_size,
                              hipStream_t stream)
{
  const float* xyz=(const float*)d_in[0];
  const float* feat=(const float*)d_in[1];
  float* out=(float*)d_out;
  float* out2=out+(size_t)NB*NS*3;     // pooled-feature region
  (void)d_ws; (void)ws_size;

  fps_kernel<<<NB,512,0,stream>>>(xyz,out);
  knn_kernel<<<NB*NS/64,256,0,stream>>>(xyz,out,out2);
  mlp_kernel<<<NB*NS/4,128,0,stream>>>(feat,xyz,out,
    (const float*)d_in[2],(const float*)d_in[3],
    (const float*)d_in[4],(const float*)d_in[5],
    (const float*)d_in[6],(const float*)d_in[7],
    (const float*)d_in[8],(const float*)d_in[9],
    (const float*)d_in[10],(const float*)d_in[11],
    (const float*)d_in[12],(const float*)d_in[13],
    (const float*)d_in[14],(const float*)d_in[15],
    (const float*)d_in[16],(const float*)d_in[17],
    (const float*)d_in[18],(const float*)d_in[19],
    out2);
}

// Round 7
// 1777.571 us; speedup vs baseline: 1.8893x; 1.3090x over previous
//
#include <hip/hip_runtime.h>

#define NB 16
#define NPTS 4096
#define NS 1024
#define NK 32
#define NCF 64

// All I/O is float32. Zero workspace bytes used. kNN parks its 32 indices
// (bit-cast to float) in the first 128B of each query's 512B output row;
// mlp_kernel reads them back and fully overwrites the row. Row ORDER of the
// 32 neighbors is irrelevant (max-pool) — only the index SET must be exact.

#define F_INF __int_as_float(0x7f800000)

#define DPP_SHR1   0x111
#define DPP_SHR2   0x112
#define DPP_SHR4   0x114
#define DPP_SHR8   0x118
#define DPP_BCAST15 0x142
#define DPP_BCAST31 0x143

// one max step of a wave64 u64-key reduction via DPP (invalid lanes keep self)
#define DPP_MAX_STEP(cur, CTRL) do{ \
  int lo_=__builtin_amdgcn_update_dpp((int)(unsigned)(cur),(int)(unsigned)(cur),CTRL,0xF,0xF,false); \
  int hi_=__builtin_amdgcn_update_dpp((int)(unsigned)((cur)>>32),(int)(unsigned)((cur)>>32),CTRL,0xF,0xF,false); \
  unsigned long long nk_=(((unsigned long long)(unsigned)hi_)<<32)|(unsigned)lo_; \
  if (nk_>(cur)) (cur)=nk_; \
}while(0)

// ---------------- FPS: 1 block/batch, 512 thr, DPP argmax ----------------
// key = (dist_bits<<32) | (4095-idx): u64 max == max dist, first index.
__global__ __launch_bounds__(512) void fps_kernel(
  const float* __restrict__ xyz, float* __restrict__ out)
{
  __shared__ float sxyz[NPTS*3];
  __shared__ unsigned long long skey[2][8];
  __shared__ int sfps[NS];
  const int b = blockIdx.x, tid = threadIdx.x;

  { // stage xyz -> LDS
    const float4* src=(const float4*)(xyz+(size_t)b*NPTS*3);
    float4* dst=(float4*)sxyz;
    for (int i=tid;i<NPTS*3/4;i+=512) dst[i]=src[i];
  }
  __syncthreads();
  // 8 points per thread in registers (ascending index with tid)
  float px[8],py[8],pz[8],dist[8];
  #pragma unroll
  for (int r=0;r<8;r++){
    int p=tid*8+r;
    px[r]=sxyz[p*3]; py[r]=sxyz[p*3+1]; pz[r]=sxyz[p*3+2];
    dist[r]=1e10f;
  }
  int far=0;
  for (int s=0;s<NS;++s){
    float cx=sxyz[far*3],cy=sxyz[far*3+1],cz=sxyz[far*3+2];
    float bv=-1.0f; int bslot=0;
    #pragma unroll
    for (int r=0;r<8;r++){
      float dx=__fsub_rn(px[r],cx);
      float dy=__fsub_rn(py[r],cy);
      float dz=__fsub_rn(pz[r],cz);
      float d2=__fadd_rn(__fadd_rn(__fmul_rn(dx,dx),__fmul_rn(dy,dy)),__fmul_rn(dz,dz));
      float nd=fminf(dist[r],d2);
      dist[r]=nd;
      if (nd>bv){bv=nd;bslot=r;}      // strict > keeps first index in lane
    }
    int bidx=tid*8+bslot;
    unsigned long long cur=(((unsigned long long)__float_as_uint(bv))<<32)
                           |(unsigned)(4095-bidx);
    DPP_MAX_STEP(cur,DPP_SHR1);
    DPP_MAX_STEP(cur,DPP_SHR2);
    DPP_MAX_STEP(cur,DPP_SHR4);
    DPP_MAX_STEP(cur,DPP_SHR8);
    DPP_MAX_STEP(cur,DPP_BCAST15);
    DPP_MAX_STEP(cur,DPP_BCAST31);
    const int par=s&1;
    if ((tid&63)==63) skey[par][tid>>6]=cur;
    __syncthreads();
    unsigned long long m=skey[par][0];
    #pragma unroll
    for (int w=1;w<8;w++){ unsigned long long o=skey[par][w]; if (o>m) m=o; }
    far=4095-(int)(m&0xFFFFFFFFu);
    if (tid==0) sfps[s]=far;
  }
  __syncthreads();
  for (int s=tid;s<NS;s+=512){
    int p=sfps[s];
    size_t o=((size_t)b*NS+s)*3;
    out[o]=sxyz[p*3]; out[o+1]=sxyz[p*3+1]; out[o+2]=sxyz[p*3+2];
  }
}

// ---------------- kNN: 256 thr (4 waves), 16 queries/block ----------------
// 16 lanes/query scan interleaved 256-pt partitions from GLOBAL (L1
// broadcast: one 192B window per wave-iteration). Per-lane sorted top-32 via
// med3 insert (values) + cmp/cndmask (indices). 4-phase LDS merge: wave ph
// dumps packed u64 (d2,idx) keys; 16 mergers 4-way merge; 4 finalize.
__global__ __launch_bounds__(256) void knn_kernel(
  const float* __restrict__ xyz, const float* __restrict__ newxyz,
  float* __restrict__ out2)
{
  __shared__ unsigned long long sdump[64*33];  // 16.9 KB (one wave's lists)
  __shared__ unsigned long long sl1[16*33];    // 4.2 KB (level-1 outputs)
  const int tid=threadIdx.x;
  const int wave=tid>>6, lane=tid&63;
  const int qw=lane>>4;               // query-within-wave 0..3
  const int part=lane&15;             // partition 0..15
  const int gq=blockIdx.x*16+wave*4+qw;
  const int b=gq>>10;
  const float* base=xyz+(size_t)b*NPTS*3;

  float ax=newxyz[(size_t)gq*3],ay=newxyz[(size_t)gq*3+1],az=newxyz[(size_t)gq*3+2];
  float a2=__fadd_rn(__fadd_rn(__fmul_rn(ax,ax),__fmul_rn(ay,ay)),__fmul_rn(az,az));
  float kD[NK]; int kI[NK];
  #pragma unroll
  for (int p=0;p<NK;p++){kD[p]=F_INF;kI[p]=0x7FFFFFFF;}
  #pragma unroll 2
  for (int t=0;t<NPTS/16;++t){
    int n=(t<<4)|part;
    float bx=base[n*3],by=base[n*3+1],bz=base[n*3+2];
    float b2=__fadd_rn(__fadd_rn(__fmul_rn(bx,bx),__fmul_rn(by,by)),__fmul_rn(bz,bz));
    float ab=__fadd_rn(__fadd_rn(__fmul_rn(ax,bx),__fmul_rn(ay,by)),__fmul_rn(az,bz));
    float tt=__fadd_rn(__fsub_rn(a2,__fmul_rn(2.0f,ab)),b2);
    float d2=fmaxf(tt,0.0f);
    if (d2<kD[NK-1]){                  // strict <: in-lane (d2,idx) stability
      #pragma unroll
      for (int p=NK-1;p>0;--p){
        bool cm1=d2<kD[p-1];
        bool cp=d2<kD[p];
        kI[p]=cm1?kI[p-1]:(cp?n:kI[p]);
        kD[p]=__builtin_fminf(__builtin_fmaxf(kD[p-1],d2),kD[p]); // med3(sorted)
      }
      if (d2<kD[0]){kD[0]=d2;kI[0]=n;}
    }
  }
  // ---- 4-phase merge
  #pragma unroll 1
  for (int ph=0;ph<4;++ph){
    if (wave==ph){
      unsigned long long* row=sdump+(size_t)lane*33;
      #pragma unroll
      for (int p=0;p<NK;p++)
        row[p]=(((unsigned long long)__float_as_uint(kD[p]))<<32)|(unsigned)kI[p];
    }
    __syncthreads();
    if (tid<16){                        // level 1: query qq, group g
      int qq=tid>>2, g=tid&3;
      const unsigned long long* r0=sdump+(size_t)(qq*16+g*4+0)*33;
      const unsigned long long* r1=sdump+(size_t)(qq*16+g*4+1)*33;
      const unsigned long long* r2=sdump+(size_t)(qq*16+g*4+2)*33;
      const unsigned long long* r3=sdump+(size_t)(qq*16+g*4+3)*33;
      unsigned long long* o=sl1+(size_t)tid*33;
      int h0=0,h1=0,h2=0,h3=0;
      unsigned long long c0=r0[0],c1=r1[0],c2=r2[0],c3=r3[0];
      for (int i=0;i<NK;++i){
        bool s01=c1<c0; unsigned long long m01=s01?c1:c0;
        bool s23=c3<c2; unsigned long long m23=s23?c3:c2;
        bool sm=m23<m01; unsigned long long m=sm?m23:m01;
        o[i]=m;
        int w=sm?(s23?3:2):(s01?1:0);
        if (w==0){h0++; c0=(h0<NK)?r0[h0]:~0ull;}
        else if (w==1){h1++; c1=(h1<NK)?r1[h1]:~0ull;}
        else if (w==2){h2++; c2=(h2<NK)?r2[h2]:~0ull;}
        else {h3++; c3=(h3<NK)?r3[h3]:~0ull;}
      }
    }
    __syncthreads();
    if (tid<4){                         // level 2 -> output indices
      const unsigned long long* r0=sl1+(size_t)(tid*4+0)*33;
      const unsigned long long* r1=sl1+(size_t)(tid*4+1)*33;
      const unsigned long long* r2=sl1+(size_t)(tid*4+2)*33;
      const unsigned long long* r3=sl1+(size_t)(tid*4+3)*33;
      float* orow=out2+(size_t)(blockIdx.x*16+ph*4+tid)*128;
      int h0=0,h1=0,h2=0,h3=0;
      unsigned long long c0=r0[0],c1=r1[0],c2=r2[0],c3=r3[0];
      for (int i=0;i<NK;++i){
        bool s01=c1<c0; unsigned long long m01=s01?c1:c0;
        bool s23=c3<c2; unsigned long long m23=s23?c3:c2;
        bool sm=m23<m01; unsigned long long m=sm?m23:m01;
        orow[i]=__int_as_float((int)(unsigned)(m&0xFFFFFFFFu));
        int w=sm?(s23?3:2):(s01?1:0);
        if (w==0){h0++; c0=(h0<NK)?r0[h0]:~0ull;}
        else if (w==1){h1++; c1=(h1<NK)?r1[h1]:~0ull;}
        else if (w==2){h2++; c2=(h2<NK)?r2[h2]:~0ull;}
        else {h3++; c3=(h3<NK)?r3[h3]:~0ull;}
      }
    }
    __syncthreads();
  }
}

// ---------------- fused group + MLP(3) + maxpool --------------------------
// 128 threads = 4 queries x 32 neighbor rows. Layer 3 in two 64-col chunks
// to keep VGPRs < 128 (no scratch spill).
__global__ __launch_bounds__(128) void mlp_kernel(
  const float* __restrict__ feat, const float* __restrict__ xyz,
  const float* __restrict__ newxyz,
  const float* __restrict__ W0,const float* __restrict__ b0,
  const float* __restrict__ g0,const float* __restrict__ be0,
  const float* __restrict__ m0,const float* __restrict__ v0,
  const float* __restrict__ W1,const float* __restrict__ b1,
  const float* __restrict__ g1,const float* __restrict__ be1,
  const float* __restrict__ m1,const float* __restrict__ v1,
  const float* __restrict__ W2,const float* __restrict__ b2,
  const float* __restrict__ g2,const float* __restrict__ be2,
  const float* __restrict__ m2,const float* __restrict__ v2,
  float* __restrict__ out2)
{
  __shared__ float sX[128*67];
  const int tid=threadIdx.x;
  const int q=blockIdx.x*4+(tid>>5);
  const int k=tid&31;
  const int b=q>>10;
  const int pt=__float_as_int(out2[(size_t)q*128+k]);

  float* myx=sX+tid*67;
  {
    const float* nx=newxyz+(size_t)q*3;
    const float* pp=xyz+((size_t)b*NPTS+pt)*3;
    myx[0]=pp[0]-nx[0]; myx[1]=pp[1]-nx[1]; myx[2]=pp[2]-nx[2];
    const float4* fp=(const float4*)(feat+((size_t)b*NPTS+pt)*NCF);
    #pragma unroll
    for (int i=0;i<16;i++){
      float4 u=fp[i]; float* d=myx+3+i*4;
      d[0]=u.x; d[1]=u.y; d[2]=u.z; d[3]=u.w;
    }
  }
  float acc[64];
  // layer 1: 67 -> 64
  #pragma unroll
  for (int c=0;c<64;c++) acc[c]=b0[c];
  #pragma unroll 2
  for (int j=0;j<67;++j){
    float xj=myx[j];
    const float* wr=W0+j*64;
    #pragma unroll
    for (int c=0;c<64;c++) acc[c]=fmaf(xj,wr[c],acc[c]);
  }
  #pragma unroll
  for (int c=0;c<64;c++){
    float A=g0[c]*rsqrtf(v0[c]+1e-3f);
    myx[c]=fmaf(A,fmaxf(acc[c],0.0f),be0[c]-m0[c]*A);
  }
  // layer 2: 64 -> 64
  #pragma unroll
  for (int c=0;c<64;c++) acc[c]=b1[c];
  #pragma unroll 2
  for (int j=0;j<64;++j){
    float xj=myx[j];
    const float* wr=W1+j*64;
    #pragma unroll
    for (int c=0;c<64;c++) acc[c]=fmaf(xj,wr[c],acc[c]);
  }
  #pragma unroll
  for (int c=0;c<64;c++){
    float A=g1[c]*rsqrtf(v1[c]+1e-3f);
    myx[c]=fmaf(A,fmaxf(acc[c],0.0f),be1[c]-m1[c]*A);
  }
  // layer 3: 64 -> 128, two 64-col chunks (keeps VGPR low)
  #pragma unroll 1
  for (int ch=0;ch<2;++ch){
    const int co=ch*64;
    #pragma unroll
    for (int c=0;c<64;c++) acc[c]=b2[co+c];
    #pragma unroll 2
    for (int j=0;j<64;++j){
      float xj=myx[j];
      const float* wr=W2+j*128+co;
      #pragma unroll
      for (int c=0;c<64;c++) acc[c]=fmaf(xj,wr[c],acc[c]);
    }
    #pragma unroll
    for (int c=0;c<64;c++){
      float A=g2[co+c]*rsqrtf(v2[co+c]+1e-3f);
      float v=fmaf(A,fmaxf(acc[c],0.0f),be2[co+c]-m2[co+c]*A);
      v=fmaxf(v,__shfl_xor(v,1));
      v=fmaxf(v,__shfl_xor(v,2));
      v=fmaxf(v,__shfl_xor(v,4));
      v=fmaxf(v,__shfl_xor(v,8));
      v=fmaxf(v,__shfl_xor(v,16));
      acc[c]=v;
    }
    if (k==0){
      float4* op=(float4*)(out2+(size_t)q*128+co);
      #pragma unroll
      for (int c=0;c<64;c+=4)
        op[c/4]=make_float4(acc[c],acc[c+1],acc[c+2],acc[c+3]);
    }
  }
}

extern "C" void kernel_launch(void* const* d_in, const int* in_sizes, int n_in,
                              void* d_out, int out_size, void* d_ws, size_t ws_size,
                              hipStream_t stream)
{
  const float* xyz=(const float*)d_in[0];
  const float* feat=(const float*)d_in[1];
  float* out=(float*)d_out;
  float* out2=out+(size_t)NB*NS*3;     // pooled-feature region
  (void)d_ws; (void)ws_size;

  fps_kernel<<<NB,512,0,stream>>>(xyz,out);
  knn_kernel<<<NB*NS/16,256,0,stream>>>(xyz,out,out2);
  mlp_kernel<<<NB*NS/4,128,0,stream>>>(feat,xyz,out,
    (const float*)d_in[2],(const float*)d_in[3],
    (const float*)d_in[4],(const float*)d_in[5],
    (const float*)d_in[6],(const float*)d_in[7],
    (const float*)d_in[8],(const float*)d_in[9],
    (const float*)d_in[10],(const float*)d_in[11],
    (const float*)d_in[12],(const float*)d_in[13],
    (const float*)d_in[14],(const float*)d_in[15],
    (const float*)d_in[16],(const float*)d_in[17],
    (const float*)d_in[18],(const float*)d_in[19],
    out2);
}

// Round 8
// 1654.813 us; speedup vs baseline: 2.0295x; 1.0742x over previous
//
#include <hip/hip_runtime.h>

#define NB 16
#define NPTS 4096
#define NS 1024
#define NK 32
#define NCF 64

// All I/O is float32. Zero workspace bytes used. kNN parks its 32 indices
// (bit-cast to float) in the first 128B of each query's 512B output row;
// mlp_kernel reads them back and fully overwrites the row. Row ORDER of the
// 32 neighbors is irrelevant (max-pool) — only the index SET must be exact.

#define F_INF __int_as_float(0x7f800000)

#define DPP_SHR1   0x111
#define DPP_SHR2   0x112
#define DPP_SHR4   0x114
#define DPP_SHR8   0x118
#define DPP_BCAST15 0x142
#define DPP_BCAST31 0x143

// one max step of a wave64 u64-key reduction via DPP (invalid lanes keep self)
#define DPP_MAX_STEP(cur, CTRL) do{ \
  int lo_=__builtin_amdgcn_update_dpp((int)(unsigned)(cur),(int)(unsigned)(cur),CTRL,0xF,0xF,false); \
  int hi_=__builtin_amdgcn_update_dpp((int)(unsigned)((cur)>>32),(int)(unsigned)((cur)>>32),CTRL,0xF,0xF,false); \
  unsigned long long nk_=(((unsigned long long)(unsigned)hi_)<<32)|(unsigned)lo_; \
  if (nk_>(cur)) (cur)=nk_; \
}while(0)

// ---------------- FPS: 1 block/batch, 256 thr, DPP argmax ----------------
// key = (dist_bits<<32) | (4095-idx): u64 max == max dist, first index.
// 256 threads (4 waves): update wall equals the 512-thr config (2 waves/SIMD
// x 144 = 4 waves... = 288 cyc) but barrier/reduce/readback terms halve.
__global__ __launch_bounds__(256) void fps_kernel(
  const float* __restrict__ xyz, float* __restrict__ out)
{
  __shared__ float sxyz[NPTS*3];
  __shared__ unsigned long long skey[2][4];
  __shared__ int sfps[NS];
  const int b = blockIdx.x, tid = threadIdx.x;

  { // stage xyz -> LDS
    const float4* src=(const float4*)(xyz+(size_t)b*NPTS*3);
    float4* dst=(float4*)sxyz;
    for (int i=tid;i<NPTS*3/4;i+=256) dst[i]=src[i];
  }
  __syncthreads();
  // 16 points per thread in registers (ascending index with tid)
  float px[16],py[16],pz[16],dist[16];
  #pragma unroll
  for (int r=0;r<16;r++){
    int p=tid*16+r;
    px[r]=sxyz[p*3]; py[r]=sxyz[p*3+1]; pz[r]=sxyz[p*3+2];
    dist[r]=1e10f;
  }
  int far=0;
  for (int s=0;s<NS;++s){
    float cx=sxyz[far*3],cy=sxyz[far*3+1],cz=sxyz[far*3+2];
    float bv=-1.0f; int bslot=0;
    #pragma unroll
    for (int r=0;r<16;r++){
      float dx=__fsub_rn(px[r],cx);
      float dy=__fsub_rn(py[r],cy);
      float dz=__fsub_rn(pz[r],cz);
      float d2=__fadd_rn(__fadd_rn(__fmul_rn(dx,dx),__fmul_rn(dy,dy)),__fmul_rn(dz,dz));
      float nd=fminf(dist[r],d2);
      dist[r]=nd;
      if (nd>bv){bv=nd;bslot=r;}      // strict > keeps first index in lane
    }
    int bidx=tid*16+bslot;
    unsigned long long cur=(((unsigned long long)__float_as_uint(bv))<<32)
                           |(unsigned)(4095-bidx);
    DPP_MAX_STEP(cur,DPP_SHR1);
    DPP_MAX_STEP(cur,DPP_SHR2);
    DPP_MAX_STEP(cur,DPP_SHR4);
    DPP_MAX_STEP(cur,DPP_SHR8);
    DPP_MAX_STEP(cur,DPP_BCAST15);
    DPP_MAX_STEP(cur,DPP_BCAST31);
    const int par=s&1;
    if ((tid&63)==63) skey[par][tid>>6]=cur;
    __syncthreads();
    unsigned long long m=skey[par][0];
    #pragma unroll
    for (int w=1;w<4;w++){ unsigned long long o=skey[par][w]; if (o>m) m=o; }
    far=4095-(int)(m&0xFFFFFFFFu);
    if (tid==0) sfps[s]=far;
  }
  __syncthreads();
  for (int s=tid;s<NS;s+=256){
    int p=sfps[s];
    size_t o=((size_t)b*NS+s)*3;
    out[o]=sxyz[p*3]; out[o+1]=sxyz[p*3+1]; out[o+2]=sxyz[p*3+2];
  }
}

// ---------------- kNN: 256 thr (4 waves), 16 queries/block ----------------
// 16 lanes/query scan interleaved 256-pt partitions from GLOBAL (L1
// broadcast). Per-lane sorted top-32 via med3 insert. __launch_bounds__
// (256,4) grants a 128-VGPR budget so kD[32]+kI[32] stay in REGISTERS
// (round-7's bare (256) capped at 64 VGPR -> scratch spill, the 5x tax).
__global__ __launch_bounds__(256, 4) void knn_kernel(
  const float* __restrict__ xyz, const float* __restrict__ newxyz,
  float* __restrict__ out2)
{
  __shared__ unsigned long long sdump[64*33];  // 16.9 KB (one wave's lists)
  __shared__ unsigned long long sl1[16*33];    // 4.2 KB (level-1 outputs)
  const int tid=threadIdx.x;
  const int wave=tid>>6, lane=tid&63;
  const int qw=lane>>4;               // query-within-wave 0..3
  const int part=lane&15;             // partition 0..15
  const int gq=blockIdx.x*16+wave*4+qw;
  const int b=gq>>10;
  const float* base=xyz+(size_t)b*NPTS*3;

  float ax=newxyz[(size_t)gq*3],ay=newxyz[(size_t)gq*3+1],az=newxyz[(size_t)gq*3+2];
  float a2=__fadd_rn(__fadd_rn(__fmul_rn(ax,ax),__fmul_rn(ay,ay)),__fmul_rn(az,az));
  float kD[NK]; int kI[NK];
  #pragma unroll
  for (int p=0;p<NK;p++){kD[p]=F_INF;kI[p]=0x7FFFFFFF;}
  #pragma unroll 2
  for (int t=0;t<NPTS/16;++t){
    int n=(t<<4)|part;
    float bx=base[n*3],by=base[n*3+1],bz=base[n*3+2];
    float b2=__fadd_rn(__fadd_rn(__fmul_rn(bx,bx),__fmul_rn(by,by)),__fmul_rn(bz,bz));
    float ab=__fadd_rn(__fadd_rn(__fmul_rn(ax,bx),__fmul_rn(ay,by)),__fmul_rn(az,bz));
    float tt=__fadd_rn(__fsub_rn(a2,__fmul_rn(2.0f,ab)),b2);
    float d2=fmaxf(tt,0.0f);
    if (d2<kD[NK-1]){                  // strict <: in-lane (d2,idx) stability
      #pragma unroll
      for (int p=NK-1;p>0;--p){
        bool cm1=d2<kD[p-1];
        bool cp=d2<kD[p];
        kI[p]=cm1?kI[p-1]:(cp?n:kI[p]);
        kD[p]=__builtin_fminf(__builtin_fmaxf(kD[p-1],d2),kD[p]); // med3(sorted)
      }
      if (d2<kD[0]){kD[0]=d2;kI[0]=n;}
    }
  }
  // ---- 4-phase merge
  #pragma unroll 1
  for (int ph=0;ph<4;++ph){
    if (wave==ph){
      unsigned long long* row=sdump+(size_t)lane*33;
      #pragma unroll
      for (int p=0;p<NK;p++)
        row[p]=(((unsigned long long)__float_as_uint(kD[p]))<<32)|(unsigned)kI[p];
    }
    __syncthreads();
    if (tid<16){                        // level 1: query qq, group g
      int qq=tid>>2, g=tid&3;
      const unsigned long long* r0=sdump+(size_t)(qq*16+g*4+0)*33;
      const unsigned long long* r1=sdump+(size_t)(qq*16+g*4+1)*33;
      const unsigned long long* r2=sdump+(size_t)(qq*16+g*4+2)*33;
      const unsigned long long* r3=sdump+(size_t)(qq*16+g*4+3)*33;
      unsigned long long* o=sl1+(size_t)tid*33;
      int h0=0,h1=0,h2=0,h3=0;
      unsigned long long c0=r0[0],c1=r1[0],c2=r2[0],c3=r3[0];
      for (int i=0;i<NK;++i){
        bool s01=c1<c0; unsigned long long m01=s01?c1:c0;
        bool s23=c3<c2; unsigned long long m23=s23?c3:c2;
        bool sm=m23<m01; unsigned long long m=sm?m23:m01;
        o[i]=m;
        int w=sm?(s23?3:2):(s01?1:0);
        if (w==0){h0++; c0=(h0<NK)?r0[h0]:~0ull;}
        else if (w==1){h1++; c1=(h1<NK)?r1[h1]:~0ull;}
        else if (w==2){h2++; c2=(h2<NK)?r2[h2]:~0ull;}
        else {h3++; c3=(h3<NK)?r3[h3]:~0ull;}
      }
    }
    __syncthreads();
    if (tid<4){                         // level 2 -> output indices
      const unsigned long long* r0=sl1+(size_t)(tid*4+0)*33;
      const unsigned long long* r1=sl1+(size_t)(tid*4+1)*33;
      const unsigned long long* r2=sl1+(size_t)(tid*4+2)*33;
      const unsigned long long* r3=sl1+(size_t)(tid*4+3)*33;
      float* orow=out2+(size_t)(blockIdx.x*16+ph*4+tid)*128;
      int h0=0,h1=0,h2=0,h3=0;
      unsigned long long c0=r0[0],c1=r1[0],c2=r2[0],c3=r3[0];
      for (int i=0;i<NK;++i){
        bool s01=c1<c0; unsigned long long m01=s01?c1:c0;
        bool s23=c3<c2; unsigned long long m23=s23?c3:c2;
        bool sm=m23<m01; unsigned long long m=sm?m23:m01;
        orow[i]=__int_as_float((int)(unsigned)(m&0xFFFFFFFFu));
        int w=sm?(s23?3:2):(s01?1:0);
        if (w==0){h0++; c0=(h0<NK)?r0[h0]:~0ull;}
        else if (w==1){h1++; c1=(h1<NK)?r1[h1]:~0ull;}
        else if (w==2){h2++; c2=(h2<NK)?r2[h2]:~0ull;}
        else {h3++; c3=(h3<NK)?r3[h3]:~0ull;}
      }
    }
    __syncthreads();
  }
}

// ---------------- fused group + MLP(3) + maxpool --------------------------
// 128 threads = 4 queries x 32 neighbor rows. Layer 3 in two 64-col chunks
// to keep VGPRs < 128 (no scratch spill).
__global__ __launch_bounds__(128) void mlp_kernel(
  const float* __restrict__ feat, const float* __restrict__ xyz,
  const float* __restrict__ newxyz,
  const float* __restrict__ W0,const float* __restrict__ b0,
  const float* __restrict__ g0,const float* __restrict__ be0,
  const float* __restrict__ m0,const float* __restrict__ v0,
  const float* __restrict__ W1,const float* __restrict__ b1,
  const float* __restrict__ g1,const float* __restrict__ be1,
  const float* __restrict__ m1,const float* __restrict__ v1,
  const float* __restrict__ W2,const float* __restrict__ b2,
  const float* __restrict__ g2,const float* __restrict__ be2,
  const float* __restrict__ m2,const float* __restrict__ v2,
  float* __restrict__ out2)
{
  __shared__ float sX[128*67];
  const int tid=threadIdx.x;
  const int q=blockIdx.x*4+(tid>>5);
  const int k=tid&31;
  const int b=q>>10;
  const int pt=__float_as_int(out2[(size_t)q*128+k]);

  float* myx=sX+tid*67;
  {
    const float* nx=newxyz+(size_t)q*3;
    const float* pp=xyz+((size_t)b*NPTS+pt)*3;
    myx[0]=pp[0]-nx[0]; myx[1]=pp[1]-nx[1]; myx[2]=pp[2]-nx[2];
    const float4* fp=(const float4*)(feat+((size_t)b*NPTS+pt)*NCF);
    #pragma unroll
    for (int i=0;i<16;i++){
      float4 u=fp[i]; float* d=myx+3+i*4;
      d[0]=u.x; d[1]=u.y; d[2]=u.z; d[3]=u.w;
    }
  }
  float acc[64];
  // layer 1: 67 -> 64
  #pragma unroll
  for (int c=0;c<64;c++) acc[c]=b0[c];
  #pragma unroll 2
  for (int j=0;j<67;++j){
    float xj=myx[j];
    const float* wr=W0+j*64;
    #pragma unroll
    for (int c=0;c<64;c++) acc[c]=fmaf(xj,wr[c],acc[c]);
  }
  #pragma unroll
  for (int c=0;c<64;c++){
    float A=g0[c]*rsqrtf(v0[c]+1e-3f);
    myx[c]=fmaf(A,fmaxf(acc[c],0.0f),be0[c]-m0[c]*A);
  }
  // layer 2: 64 -> 64
  #pragma unroll
  for (int c=0;c<64;c++) acc[c]=b1[c];
  #pragma unroll 2
  for (int j=0;j<64;++j){
    float xj=myx[j];
    const float* wr=W1+j*64;
    #pragma unroll
    for (int c=0;c<64;c++) acc[c]=fmaf(xj,wr[c],acc[c]);
  }
  #pragma unroll
  for (int c=0;c<64;c++){
    float A=g1[c]*rsqrtf(v1[c]+1e-3f);
    myx[c]=fmaf(A,fmaxf(acc[c],0.0f),be1[c]-m1[c]*A);
  }
  // layer 3: 64 -> 128, two 64-col chunks (keeps VGPR low)
  #pragma unroll 1
  for (int ch=0;ch<2;++ch){
    const int co=ch*64;
    #pragma unroll
    for (int c=0;c<64;c++) acc[c]=b2[co+c];
    #pragma unroll 2
    for (int j=0;j<64;++j){
      float xj=myx[j];
      const float* wr=W2+j*128+co;
      #pragma unroll
      for (int c=0;c<64;c++) acc[c]=fmaf(xj,wr[c],acc[c]);
    }
    #pragma unroll
    for (int c=0;c<64;c++){
      float A=g2[co+c]*rsqrtf(v2[co+c]+1e-3f);
      float v=fmaf(A,fmaxf(acc[c],0.0f),be2[co+c]-m2[co+c]*A);
      v=fmaxf(v,__shfl_xor(v,1));
      v=fmaxf(v,__shfl_xor(v,2));
      v=fmaxf(v,__shfl_xor(v,4));
      v=fmaxf(v,__shfl_xor(v,8));
      v=fmaxf(v,__shfl_xor(v,16));
      acc[c]=v;
    }
    if (k==0){
      float4* op=(float4*)(out2+(size_t)q*128+co);
      #pragma unroll
      for (int c=0;c<64;c+=4)
        op[c/4]=make_float4(acc[c],acc[c+1],acc[c+2],acc[c+3]);
    }
  }
}

extern "C" void kernel_launch(void* const* d_in, const int* in_sizes, int n_in,
                              void* d_out, int out_size, void* d_ws, size_t ws_size,
                              hipStream_t stream)
{
  const float* xyz=(const float*)d_in[0];
  const float* feat=(const float*)d_in[1];
  float* out=(float*)d_out;
  float* out2=out+(size_t)NB*NS*3;     // pooled-feature region
  (void)d_ws; (void)ws_size;

  fps_kernel<<<NB,256,0,stream>>>(xyz,out);
  knn_kernel<<<NB*NS/16,256,0,stream>>>(xyz,out,out2);
  mlp_kernel<<<NB*NS/4,128,0,stream>>>(feat,xyz,out,
    (const float*)d_in[2],(const float*)d_in[3],
    (const float*)d_in[4],(const float*)d_in[5],
    (const float*)d_in[6],(const float*)d_in[7],
    (const float*)d_in[8],(const float*)d_in[9],
    (const float*)d_in[10],(const float*)d_in[11],
    (const float*)d_in[12],(const float*)d_in[13],
    (const float*)d_in[14],(const float*)d_in[15],
    (const float*)d_in[16],(const float*)d_in[17],
    (const float*)d_in[18],(const float*)d_in[19],
    out2);
}